// Round 1
// baseline (729.967 us; speedup 1.0000x reference)
//
#include <hip/hip_runtime.h>
#include <stdint.h>

// ---------------------------------------------------------------------------
// HarmonicStructureDiscriminator on MI355X (gfx950)
// Pipeline: STFT(512/256) -> log-shift lower (KF=7) -> conv1x7(14->64)
//           -> 8x dilated conv3x3(64->64, d=1..8) -> conv3x3(64->1)
// All activations NHWC bf16 on a 273x273 canvas (halo 8, zeroed) so dilated
// convs read padding for free.  Convs = implicit GEMM with
// mfma_f32_16x16x32_bf16 (A[m=lane&15][k=q*8+j], B[k][n=lane&15],
// D col=lane&15,row=q*4+reg  -- m89/m101-verified layouts).
// ---------------------------------------------------------------------------

typedef __attribute__((ext_vector_type(8))) short bf16x8;
typedef __attribute__((ext_vector_type(4))) float f32x4;
typedef __attribute__((ext_vector_type(4))) int   i32x4;

#define HCV 273           // canvas rows   (8 + 257 + 8)
#define TCV 273           // canvas cols
#define NBATCH 4
#define FV 257
#define TVD 257

static constexpr size_t CAN_ELEMS  = (size_t)NBATCH * HCV * TCV * 64;   // bf16 elems
static constexpr size_t CAN_BYTES  = CAN_ELEMS * 2;                     // 38,158,848
static constexpr size_t LOW_BYTES  = (size_t)NBATCH * HCV * TCV * 14 * 2; // 8,347,248
static constexpr size_t SPEC_BYTES = (size_t)NBATCH * 257 * 257 * 2 * 4;  // 2,113,568
static constexpr size_t W1N_BYTES  = 64 * 128 * 2;
static constexpr size_t WLN_BYTES  = 8 * 9 * 64 * 64 * 2;
static constexpr size_t WLAST_BYTES = 576 * 4;

static __device__ __forceinline__ unsigned short f2bf(float f) {
  union { float f; unsigned u; } v; v.f = f;
  unsigned r = v.u + 0x7FFFu + ((v.u >> 16) & 1u);   // RNE
  return (unsigned short)(r >> 16);
}
static __device__ __forceinline__ float bflo(int u) {
  union { unsigned u; float f; } v; v.u = ((unsigned)u) << 16; return v.f;
}
static __device__ __forceinline__ float bfhi(int u) {
  union { unsigned u; float f; } v; v.u = ((unsigned)u) & 0xFFFF0000u; return v.f;
}

// ---------------------------------------------------------------------------
// Weight normalization: w = g * v / ||v||_per_oc , written transposed+bf16.
// blocks 0..63: conv1 (k = kw*14+ch, padded to 128)
// blocks 64..575: 8 layers x 64 oc -> wln[l][tap][oc][ic]
// block 576: last conv -> fp32 [tap][ic]
// ---------------------------------------------------------------------------
__global__ __launch_bounds__(256) void wnorm_kernel(
    const float* v_h, const float* g_h,
    const float* vs, const float* gs,
    const float* v_last, const float* g_last,
    unsigned short* w1n, unsigned short* wln, float* wlast) {
  __shared__ float red[256];
  int bid = blockIdx.x, tid = threadIdx.x;
  if (bid < 64) {
    int oc = bid;
    const float* v = v_h + oc * 98;       // [ch][kw] = [14][7]
    float s = 0.f;
    for (int i = tid; i < 98; i += 256) s += v[i] * v[i];
    red[tid] = s; __syncthreads();
    for (int off = 128; off > 0; off >>= 1) { if (tid < off) red[tid] += red[tid + off]; __syncthreads(); }
    float scale = g_h[oc] / sqrtf(red[0]);
    for (int k = tid; k < 128; k += 256) {
      unsigned short val = 0;
      if (k < 98) { int kw = k / 14, ch = k - kw * 14; val = f2bf(v[ch * 7 + kw] * scale); }
      w1n[oc * 128 + k] = val;
    }
  } else if (bid < 576) {
    int l = (bid - 64) >> 6, oc = (bid - 64) & 63;
    const float* v = vs + ((size_t)(l * 64 + oc)) * 576;  // [ic][kh][kw]
    float s = 0.f;
    for (int i = tid; i < 576; i += 256) s += v[i] * v[i];
    red[tid] = s; __syncthreads();
    for (int off = 128; off > 0; off >>= 1) { if (tid < off) red[tid] += red[tid + off]; __syncthreads(); }
    float scale = gs[l * 64 + oc] / sqrtf(red[0]);
    for (int i = tid; i < 576; i += 256) {
      int ic = i / 9, tap = i - ic * 9;
      wln[(((size_t)l * 9 + tap) * 64 + oc) * 64 + ic] = f2bf(v[i] * scale);
    }
  } else {
    const float* v = v_last;              // [ic][kh][kw], 576
    float s = 0.f;
    for (int i = tid; i < 576; i += 256) s += v[i] * v[i];
    red[tid] = s; __syncthreads();
    for (int off = 128; off > 0; off >>= 1) { if (tid < off) red[tid] += red[tid + off]; __syncthreads(); }
    float scale = g_last[0] / sqrtf(red[0]);
    for (int i = tid; i < 576; i += 256) {
      int ic = i / 9, tap = i - ic * 9;
      wlast[tap * 64 + ic] = v[i] * scale;
    }
  }
}

// ---------------------------------------------------------------------------
// STFT: one block per (b, frame).  Reflect pad + Hann window fused into the
// bit-reversed load; radix-2 DIT FFT in LDS (fp32).  Output spec[b][t][f][2].
// ---------------------------------------------------------------------------
__global__ __launch_bounds__(256) void stft_kernel(const float* __restrict__ x,
                                                   float* __restrict__ spec) {
  __shared__ float re[512];
  __shared__ float im[512];
  int bid = blockIdx.x;
  int b = bid / 257, fr = bid % 257;
  const float* xb = x + (size_t)b * 65536;
  int tid = threadIdx.x;
  for (int ii = 0; ii < 2; ii++) {
    int n = tid + ii * 256;
    int s = __brev((unsigned)n) >> 23;          // 9-bit bit-reverse
    int j = fr * 256 + s - 256;                 // reflect pad index
    int ja = j < 0 ? -j : (j >= 65536 ? 131070 - j : j);
    float w = 0.5f - 0.5f * cosf(6.283185307179586f * (float)s / 512.0f);
    re[n] = xb[ja] * w;
    im[n] = 0.f;
  }
  __syncthreads();
  for (int st = 0; st < 9; st++) {
    int half = 1 << st;
    int p = tid & (half - 1);
    int g = tid >> st;
    int i0 = (g << (st + 1)) + p;
    int i1 = i0 + half;
    float ang = -6.283185307179586f * (float)p / (float)(2 << st);
    float sv, cv; sincosf(ang, &sv, &cv);
    float br = re[i1], bi = im[i1];
    float tr = cv * br - sv * bi;
    float ti = cv * bi + sv * br;
    float ar = re[i0], ai = im[i0];
    re[i1] = ar - tr; im[i1] = ai - ti;
    re[i0] = ar + tr; im[i0] = ai + ti;
    __syncthreads();
  }
  for (int k = tid; k < 257; k += 256) {
    float* o = spec + (((size_t)b * 257 + fr) * 257 + k) * 2;
    o[0] = re[k];
    o[1] = im[k];
  }
}

// ---------------------------------------------------------------------------
// Harmonic lowering: low[b][f][t][kf*2+c] (NHWC bf16 canvas, halo 8).
// ---------------------------------------------------------------------------
__global__ __launch_bounds__(256) void lower_kernel(const float* __restrict__ spec,
                                                    unsigned short* __restrict__ low) {
  int idx = blockIdx.x * 256 + threadIdx.x;
  if (idx >= 4 * 66049) return;
  int b = idx / 66049, r = idx % 66049, f = r / 257, t = r % 257;
  const float shifts[7] = {1945.9101090932196f, 1252.7629684953681f, 847.2978603872037f,
                           559.6157879354227f, 336.4722366212129f, 154.15067982725836f, 0.0f};
  const float* sp = spec + ((size_t)(b * 257 + t)) * 257 * 2;
  unsigned short* lp = low + (((size_t)b * HCV + f + 8) * TCV + t + 8) * 14;
  for (int kf = 0; kf < 7; kf++) {
    float src = (float)f - shifts[kf];
    float lo = floorf(src);
    int li = (int)lo;
    float fr = src - lo;
    float g0r = 0.f, g0i = 0.f, g1r = 0.f, g1i = 0.f;
    if (li >= 0 && li < 257) { g0r = sp[li * 2]; g0i = sp[li * 2 + 1]; }
    if (li + 1 >= 0 && li + 1 < 257) { g1r = sp[(li + 1) * 2]; g1i = sp[(li + 1) * 2 + 1]; }
    float vr = (1.f - fr) * g0r + fr * g1r;
    float vi = (1.f - fr) * g0i + fr * g1i;
    lp[kf * 2 + 0] = f2bf(vr);
    lp[kf * 2 + 1] = f2bf(vi);
  }
}

// ---------------------------------------------------------------------------
// conv1: 14->64, kernel 1x7, pad_w=3.  im2col into LDS (K padded 98->128),
// MFMA GEMM M=64(t) N=64(oc) K=128.  5 t-chunks (last masked).
// ---------------------------------------------------------------------------
__global__ __launch_bounds__(256) void conv1_kernel(const unsigned short* __restrict__ low,
                                                    const unsigned short* __restrict__ w1n,
                                                    const float* __restrict__ b_h,
                                                    unsigned short* __restrict__ outc) {
  __shared__ unsigned short Al[64 * 128];
  __shared__ unsigned short Bl[64 * 128];
  int bid = blockIdx.x;
  int chunk = bid % 5, bf = bid / 5, f = bf % 257, b = bf / 257;
  int t0 = chunk * 64;
  int tid = threadIdx.x;
  for (int i = tid; i < 1024; i += 256) ((i32x4*)Bl)[i] = ((const i32x4*)w1n)[i];
  const unsigned short* lowrow = low + ((size_t)(b * HCV + f + 8)) * TCV * 14;
  for (int i = tid; i < 8192; i += 256) {
    int m = i >> 7, k = i & 127;
    unsigned short val = 0;
    if (k < 98) {
      int kw = k / 14, ch = k - kw * 14;
      int ct = t0 + m + kw - 3 + 8;           // >= 5 always
      if (ct < TCV) val = lowrow[ct * 14 + ch];
    }
    Al[i] = val;
  }
  __syncthreads();
  int lane = tid & 63, wv = tid >> 6;
  int lrow = lane & 15, q = lane >> 4;
  int m0 = wv * 16;
  f32x4 acc[4] = {f32x4{0,0,0,0}, f32x4{0,0,0,0}, f32x4{0,0,0,0}, f32x4{0,0,0,0}};
#pragma unroll
  for (int ks = 0; ks < 4; ks++) {
    bf16x8 a = *(const bf16x8*)&Al[(m0 + lrow) * 128 + ks * 32 + q * 8];
#pragma unroll
    for (int nt = 0; nt < 4; nt++) {
      bf16x8 bb = *(const bf16x8*)&Bl[(nt * 16 + lrow) * 128 + ks * 32 + q * 8];
      acc[nt] = __builtin_amdgcn_mfma_f32_16x16x32_bf16(a, bb, acc[nt], 0, 0, 0);
    }
  }
  int tb = t0 + m0 + q * 4;
  unsigned short* orow = outc + ((size_t)(b * HCV + f + 8)) * TCV * 64;
#pragma unroll
  for (int nt = 0; nt < 4; nt++) {
    int oc = nt * 16 + lrow;
    float bv = b_h[oc];
#pragma unroll
    for (int rg = 0; rg < 4; rg++) {
      int t = tb + rg;
      if (t < 257) {
        float v = acc[nt][rg] + bv;
        v = v > 0.f ? v : 0.2f * v;
        orow[(size_t)(t + 8) * 64 + oc] = f2bf(v);
      }
    }
  }
}

// ---------------------------------------------------------------------------
// Dilated 3x3 conv 64->64 + bias + leaky.  Block = (b, f, t-chunk of 64).
// K = 9 taps x 64 ic processed in two ic-halves (LDS 52KB -> 3 blocks/CU).
// t in [0,256) only -- t=256 column done by edge_kernel (no masks here).
// ---------------------------------------------------------------------------
__global__ __launch_bounds__(256) void conv3_kernel(const unsigned short* __restrict__ inc,
                                                    const unsigned short* __restrict__ wl,
                                                    const float* __restrict__ bias,
                                                    unsigned short* __restrict__ outc,
                                                    int d) {
  __shared__ unsigned short Xs[3 * 80 * 32];   // [row3][t 80][ic-half 32]
  __shared__ unsigned short Ws[9 * 64 * 32];   // [tap][oc][ic-half 32]
  int bid = blockIdx.x;
  int chunk = bid & 3, bf = bid >> 2, f = bf % 257, b = bf / 257;
  int t0 = chunk << 6;
  int tid = threadIdx.x;
  int lane = tid & 63, wv = tid >> 6;
  int lrow = lane & 15, q = lane >> 4;
  int m0 = wv << 4;
  f32x4 acc[4] = {f32x4{0,0,0,0}, f32x4{0,0,0,0}, f32x4{0,0,0,0}, f32x4{0,0,0,0}};

#pragma unroll
  for (int h = 0; h < 2; h++) {
    if (h) __syncthreads();                    // protect LDS restage
    // stage weights half: 2304 int4
    for (int i = tid; i < 2304; i += 256) {
      int to = i >> 2, icq = i & 3;
      ((i32x4*)Ws)[i] = *(const i32x4*)&wl[(size_t)to * 64 + h * 32 + icq * 8];
    }
    // stage input half: 960 int4
    for (int i = tid; i < 960; i += 256) {
      int icq = i & 3, tt = (i >> 2) % 80, rr = (i >> 2) / 80;
      int row = f + 8 + (rr - 1) * d;
      int ct = t0 + tt;
      ((i32x4*)Xs)[i] = *(const i32x4*)&inc[(((size_t)b * HCV + row) * TCV + ct) * 64 + h * 32 + icq * 8];
    }
    __syncthreads();
#pragma unroll
    for (int tap = 0; tap < 9; tap++) {
      int kh = tap / 3, kw = tap - kh * 3;
      int tt = m0 + lrow + 8 + (kw - 1) * d;
      bf16x8 a = *(const bf16x8*)&Xs[(kh * 80 + tt) * 32 + q * 8];
#pragma unroll
      for (int nt = 0; nt < 4; nt++) {
        bf16x8 bb = *(const bf16x8*)&Ws[(tap * 64 + nt * 16 + lrow) * 32 + q * 8];
        acc[nt] = __builtin_amdgcn_mfma_f32_16x16x32_bf16(a, bb, acc[nt], 0, 0, 0);
      }
    }
  }
  int tb = t0 + m0 + q * 4;                    // <= 255, no mask needed
  unsigned short* orow = outc + (((size_t)b * HCV + f + 8) * TCV + 8) * 64;
#pragma unroll
  for (int nt = 0; nt < 4; nt++) {
    int oc = nt * 16 + lrow;
    float bv = bias[oc];
#pragma unroll
    for (int rg = 0; rg < 4; rg++) {
      float v = acc[nt][rg] + bv;
      v = v > 0.f ? v : 0.2f * v;
      orow[(size_t)(tb + rg) * 64 + oc] = f2bf(v);
    }
  }
}

// t=256 edge column of each dilated conv.  1 wave per (b,f), thread = oc.
__global__ __launch_bounds__(64) void edge_kernel(const unsigned short* __restrict__ inc,
                                                  const unsigned short* __restrict__ wl,
                                                  const float* __restrict__ bias,
                                                  unsigned short* __restrict__ outc,
                                                  int d) {
  int b = blockIdx.x / 257, f = blockIdx.x % 257;
  int oc = threadIdx.x;
  float acc = 0.f;
#pragma unroll
  for (int tap = 0; tap < 9; tap++) {
    int kh = tap / 3, kw = tap - kh * 3;
    int row = f + 8 + (kh - 1) * d;
    int ct = 264 + (kw - 1) * d;
    const unsigned short* xp = &inc[(((size_t)b * HCV + row) * TCV + ct) * 64];
    const unsigned short* wp = &wl[(size_t)(tap * 64 + oc) * 64];
    for (int icq = 0; icq < 8; icq++) {
      i32x4 xv = *(const i32x4*)&xp[icq * 8];
      i32x4 wv = *(const i32x4*)&wp[icq * 8];
#pragma unroll
      for (int j = 0; j < 4; j++) {
        acc += bflo(xv[j]) * bflo(wv[j]) + bfhi(xv[j]) * bfhi(wv[j]);
      }
    }
  }
  acc += bias[oc];
  acc = acc > 0.f ? acc : 0.2f * acc;
  outc[(((size_t)b * HCV + f + 8) * TCV + 264) * 64 + oc] = f2bf(acc);
}

// Last conv 64->1, 3x3, pad 1, no activation, fp32 weights, writes d_out.
__global__ __launch_bounds__(256) void last_kernel(const unsigned short* __restrict__ inc,
                                                   const float* __restrict__ wlast,
                                                   const float* __restrict__ b_last,
                                                   float* __restrict__ out) {
  int idx = blockIdx.x * 256 + threadIdx.x;
  if (idx >= 4 * 66049) return;
  int b = idx / 66049, r = idx % 66049, f = r / 257, t = r % 257;
  float acc = b_last[0];
#pragma unroll
  for (int kh = 0; kh < 3; kh++) {
#pragma unroll
    for (int kw = 0; kw < 3; kw++) {
      const unsigned short* xp = &inc[(((size_t)b * HCV + f + 8 + kh - 1) * TCV + t + 8 + kw - 1) * 64];
      const float* wp = &wlast[(kh * 3 + kw) * 64];
      for (int icq = 0; icq < 8; icq++) {
        i32x4 xv = *(const i32x4*)&xp[icq * 8];
#pragma unroll
        for (int j = 0; j < 4; j++) {
          acc += bflo(xv[j]) * wp[icq * 8 + 2 * j] + bfhi(xv[j]) * wp[icq * 8 + 2 * j + 1];
        }
      }
    }
  }
  out[idx] = acc;
}

extern "C" void kernel_launch(void* const* d_in, const int* in_sizes, int n_in,
                              void* d_out, int out_size, void* d_ws, size_t ws_size,
                              hipStream_t stream) {
  const float* x      = (const float*)d_in[0];
  const float* v_h    = (const float*)d_in[1];
  const float* g_h    = (const float*)d_in[2];
  const float* b_h    = (const float*)d_in[3];
  const float* vs     = (const float*)d_in[4];
  const float* gs     = (const float*)d_in[5];
  const float* bs     = (const float*)d_in[6];
  const float* v_last = (const float*)d_in[7];
  const float* g_last = (const float*)d_in[8];
  const float* b_last = (const float*)d_in[9];

  char* ws = (char*)d_ws;
  unsigned short* canvasA = (unsigned short*)ws;
  unsigned short* canvasB = (unsigned short*)(ws + CAN_BYTES);
  unsigned short* low     = canvasB;                         // aliased; re-zeroed after conv1
  float*          spec    = (float*)(ws + 2 * CAN_BYTES);
  unsigned short* w1n     = (unsigned short*)(ws + 2 * CAN_BYTES + SPEC_BYTES);
  unsigned short* wln     = (unsigned short*)(ws + 2 * CAN_BYTES + SPEC_BYTES + W1N_BYTES);
  float*          wlast   = (float*)(ws + 2 * CAN_BYTES + SPEC_BYTES + W1N_BYTES + WLN_BYTES);
  float*          out     = (float*)d_out;

  // zero both canvases (halo correctness); ws is poisoned 0xAA each call
  hipMemsetAsync(ws, 0, 2 * CAN_BYTES, stream);

  wnorm_kernel<<<577, 256, 0, stream>>>(v_h, g_h, vs, gs, v_last, g_last, w1n, wln, wlast);
  stft_kernel<<<4 * 257, 256, 0, stream>>>(x, spec);
  lower_kernel<<<(4 * 66049 + 255) / 256, 256, 0, stream>>>(spec, low);
  conv1_kernel<<<4 * 257 * 5, 256, 0, stream>>>(low, w1n, b_h, canvasA);

  // low region was inside canvasB: restore its zeros before layer 1 writes B
  hipMemsetAsync(canvasB, 0, LOW_BYTES, stream);

  unsigned short* cur = canvasA;
  unsigned short* nxt = canvasB;
  for (int l = 0; l < 8; l++) {
    int d = l + 1;
    const unsigned short* w = wln + (size_t)l * 9 * 64 * 64;
    const float* bb = bs + l * 64;
    conv3_kernel<<<4 * 257 * 4, 256, 0, stream>>>(cur, w, bb, nxt, d);
    edge_kernel<<<4 * 257, 64, 0, stream>>>(cur, w, bb, nxt, d);
    unsigned short* tmp = cur; cur = nxt; nxt = tmp;
  }

  last_kernel<<<(4 * 66049 + 255) / 256, 256, 0, stream>>>(cur, wlast, b_last, out);
}